// Round 11
// baseline (226.453 us; speedup 1.0000x reference)
//
#include <hip/hip_runtime.h>

typedef __attribute__((ext_vector_type(8))) short bh8;   // 8 x bf16 (16B)
typedef __attribute__((ext_vector_type(4))) float f4;

static __device__ __forceinline__ float b2f(unsigned short u){
  union { unsigned int i; float f; } c; c.i = ((unsigned int)u) << 16; return c.f;
}
static __device__ __forceinline__ unsigned short f2b(float f){
  union { float f; unsigned int i; } c; c.f = f;
  unsigned int u = c.i; u += 0x7fffu + ((u >> 16) & 1u);
  return (unsigned short)(u >> 16);
}
static __device__ __forceinline__ float elu1(float x){ return x > 0.f ? x : (__expf(x) - 1.f); }
static __device__ __forceinline__ float lrelu(float x){ return x > 0.f ? x : 0.2f * x; }
static __device__ __forceinline__ float gload(const void* p, size_t i, int isf32){
  return isf32 ? ((const float*)p)[i] : b2f(((const unsigned short*)p)[i]);
}
// per-wave dtype vote: sample 64 words of W0; bf16 -> low u16 is a plausible small
// bf16 (exp 100..126) ~64/64; fp32 -> low u16 is mantissa noise (~10%).
static __device__ __forceinline__ int detect_f32(const unsigned int* __restrict__ W0w, int lane){
  unsigned int w = W0w[lane & 63];
  unsigned int e = (w >> 7) & 0xFFu;
  unsigned long long m = __ballot(e >= 100u && e <= 126u);
  return (__popcll(m) < 32) ? 1 : 0;
}

// ---------------- prep: bf16 transposed + augmented weight tables ----------------
// Wt1 [272][256]: c<256 -> W0[h=c>>5][k][d=c&31]
//                 c in [256,264): h: sum_d W0[h][k][d]*a0[h][d]      (s_src)
//                 c in [264,272): h: sum_d W0[h][k][d]*a0[h][32+d]   (s_dst)
// Wt2 [80][256]:  c<64 -> W1[k][c]; c==64: W1[k][:].a1[:64]; c==65: .a1[64:]; rest 0
__global__ __launch_bounds__(256) void prep_kernel(
    const void* __restrict__ W0, const void* __restrict__ a0,
    const void* __restrict__ W1, const void* __restrict__ a1,
    unsigned short* __restrict__ Wt1, unsigned short* __restrict__ Wt2){
  int isf = detect_f32((const unsigned int*)W0, threadIdx.x & 63);
  int c = blockIdx.x, k = threadIdx.x;
  if (c < 272){
    float v;
    if (c < 256){
      int h = c >> 5, d = c & 31;
      v = gload(W0, (size_t)(h*256 + k)*32 + d, isf);
    } else if (c < 264){
      int h = c - 256; float s = 0.f;
      for (int d = 0; d < 32; d++)
        s += gload(W0, (size_t)(h*256 + k)*32 + d, isf) * gload(a0, h*64 + d, isf);
      v = s;
    } else {
      int h = c - 264; float s = 0.f;
      for (int d = 0; d < 32; d++)
        s += gload(W0, (size_t)(h*256 + k)*32 + d, isf) * gload(a0, h*64 + 32 + d, isf);
      v = s;
    }
    Wt1[c*256 + k] = f2b(v);
  } else {
    int c2 = c - 272; float v;
    if (c2 < 64) v = gload(W1, k*64 + c2, isf);
    else if (c2 == 64){ float s = 0.f; for (int i = 0; i < 64; i++) s += gload(W1, k*64+i, isf) * gload(a1, i, isf);      v = s; }
    else if (c2 == 65){ float s = 0.f; for (int i = 0; i < 64; i++) s += gload(W1, k*64+i, isf) * gload(a1, 64 + i, isf); v = s; }
    else v = 0.f;
    Wt2[c2*256 + k] = f2b(v);
  }
}

// ---------------- GEMM1 v4 (unchanged): LDS A-tile, register B, in-place C + bulk store ----
__global__ __launch_bounds__(256, 2) void gemm1_mfma(
    const void* __restrict__ Xraw, const unsigned short* __restrict__ Wt,
    unsigned short* __restrict__ H1, float* __restrict__ S1, int N,
    const void* __restrict__ W0){
  __shared__ __align__(16) unsigned short A[112*264];
  int tid = threadIdx.x, wv = tid >> 6, lane = tid & 63;
  int isf = detect_f32((const unsigned int*)W0, lane);
  int q = lane >> 4, l = lane & 15;
  int n0 = blockIdx.x*112;
  #pragma unroll
  for (int it = 0; it < 14; it++){
    int g = it*256 + tid;
    int r = g >> 5, c = g & 31;
    int grow = n0 + r; if (grow > N-1) grow = N-1;
    bh8 v;
    if (isf){
      const float* xr = (const float*)Xraw + (size_t)grow*256 + c*8;
      float4 u0 = *(const float4*)xr, u1 = *(const float4*)(xr + 4);
      v[0]=(short)f2b(u0.x); v[1]=(short)f2b(u0.y); v[2]=(short)f2b(u0.z); v[3]=(short)f2b(u0.w);
      v[4]=(short)f2b(u1.x); v[5]=(short)f2b(u1.y); v[6]=(short)f2b(u1.z); v[7]=(short)f2b(u1.w);
    } else {
      v = *(const bh8*)((const unsigned short*)Xraw + (size_t)grow*256 + c*8);
    }
    *(bh8*)&A[r*264 + c*8] = v;
  }
  __syncthreads();
  const bh8* Wb = (const bh8*)Wt;
  bh8 B[4][8];
  #pragma unroll
  for (int tt = 0; tt < 4; tt++){
    int t = wv*4 + tt;
    #pragma unroll
    for (int kk = 0; kk < 8; kk++) B[tt][kk] = Wb[(size_t)(t*16 + l)*32 + kk*4 + q];
  }
  bh8 Bs[8];
  if (wv == 0){
    #pragma unroll
    for (int kk = 0; kk < 8; kk++) Bs[kk] = Wb[(size_t)(256 + l)*32 + kk*4 + q];
  }
  for (int m = 0; m < 7; m++){
    bh8 a[8];
    #pragma unroll
    for (int kk = 0; kk < 8; kk++) a[kk] = *(const bh8*)&A[(m*16 + l)*264 + kk*32 + q*8];
    f4 acc[4];
    #pragma unroll
    for (int tt = 0; tt < 4; tt++){
      f4 z = {0.f,0.f,0.f,0.f}; acc[tt] = z;
      #pragma unroll
      for (int kk = 0; kk < 8; kk++)
        acc[tt] = __builtin_amdgcn_mfma_f32_16x16x32_bf16(a[kk], B[tt][kk], acc[tt], 0, 0, 0);
    }
    if (wv == 0){
      f4 as = {0.f,0.f,0.f,0.f};
      #pragma unroll
      for (int kk = 0; kk < 8; kk++)
        as = __builtin_amdgcn_mfma_f32_16x16x32_bf16(a[kk], Bs[kk], as, 0, 0, 0);
      #pragma unroll
      for (int r = 0; r < 4; r++){
        int row = n0 + m*16 + q*4 + r;
        if (row < N) S1[(size_t)row*16 + l] = as[r];   // l<8: s_src[h], l>=8: s_dst[h]
      }
    }
    __syncthreads();
    #pragma unroll
    for (int tt = 0; tt < 4; tt++){
      int t = wv*4 + tt;
      #pragma unroll
      for (int r = 0; r < 4; r++)
        A[(m*16 + q*4 + r)*264 + t*16 + l] = f2b(acc[tt][r]);
    }
    __syncthreads();
  }
  #pragma unroll
  for (int g = 0; g < 14; g++){
    int idx = g*256 + tid;
    int r = idx >> 5, c = idx & 31;
    int row = n0 + r;
    if (row < N)
      *(bh8*)(H1 + (size_t)row*256 + c*8) = *(const bh8*)&A[r*264 + c*8];
  }
}

// ---------------- FUSED agg1 + gemm2 (R9 32-node version + block offset) ----------------
__global__ __launch_bounds__(256) void fused_agg1_gemm2(
    const float* __restrict__ S1, const unsigned short* __restrict__ H1,
    const int* __restrict__ dst, const unsigned short* __restrict__ Wt2,
    unsigned short* __restrict__ H2, float* __restrict__ S2, int N, int b0){
  __shared__ __align__(16) unsigned short Xt[32*264];
  __shared__ __align__(16) unsigned short Hs[32*88];
  int tid = threadIdx.x, wv = tid >> 6, lane = tid & 63;
  int n0 = (blockIdx.x + b0)*32;
  int h = lane >> 3, jj = lane & 7;
  int half = lane >> 5, li = lane & 31;
  int cb = li*8, hc = li >> 2;
  for (int np = 0; np < 4; np++){
    int lrA = wv*8 + np*2, lrB = lrA + 1;
    int nodeA = n0 + lrA; if (nodeA > N-1) nodeA = N-1;
    int nodeB = n0 + lrB; if (nodeB > N-1) nodeB = N-1;
    const int* dpA = dst + (size_t)nodeA*16;
    const int* dpB = dst + (size_t)nodeB*16;
    int d0A = dpA[jj], d1A = dpA[jj + 8];
    int d0B = dpB[jj], d1B = dpB[jj + 8];
    float ssA = S1[(size_t)nodeA*16 + h];
    float ssB = S1[(size_t)nodeB*16 + h];
    float e0A = lrelu(ssA + S1[(size_t)d0A*16 + 8 + h]);
    float e1A = lrelu(ssA + S1[(size_t)d1A*16 + 8 + h]);
    float e0B = lrelu(ssB + S1[(size_t)d0B*16 + 8 + h]);
    float e1B = lrelu(ssB + S1[(size_t)d1B*16 + 8 + h]);
    float mA = fmaxf(e0A, e1A), mB = fmaxf(e0B, e1B);
    mA = fmaxf(mA, __shfl_xor(mA, 1)); mB = fmaxf(mB, __shfl_xor(mB, 1));
    mA = fmaxf(mA, __shfl_xor(mA, 2)); mB = fmaxf(mB, __shfl_xor(mB, 2));
    mA = fmaxf(mA, __shfl_xor(mA, 4)); mB = fmaxf(mB, __shfl_xor(mB, 4));
    float p0A = __expf(e0A - mA), p1A = __expf(e1A - mA);
    float p0B = __expf(e0B - mB), p1B = __expf(e1B - mB);
    float sA = p0A + p1A, sB = p0B + p1B;
    sA += __shfl_xor(sA, 1); sB += __shfl_xor(sB, 1);
    sA += __shfl_xor(sA, 2); sB += __shfl_xor(sB, 2);
    sA += __shfl_xor(sA, 4); sB += __shfl_xor(sB, 4);
    float invA = 1.f / sA, invB = 1.f / sB;
    float v0A = p0A * invA, v1A = p1A * invA;
    float v0B = p0B * invB, v1B = p1B * invB;
    float accA[8] = {0.f,0.f,0.f,0.f,0.f,0.f,0.f,0.f};
    float accB[8] = {0.f,0.f,0.f,0.f,0.f,0.f,0.f,0.f};
    #pragma unroll
    for (int i = 0; i < 8; i++){
      int j  = i*2 + half;
      int jl = j & 7;
      int rowA  = (i < 4) ? __shfl(d0A, jl) : __shfl(d1A, jl);
      int rowB  = (i < 4) ? __shfl(d0B, jl) : __shfl(d1B, jl);
      float awA = (i < 4) ? __shfl(v0A, hc*8 + jl) : __shfl(v1A, hc*8 + jl);
      float awB = (i < 4) ? __shfl(v0B, hc*8 + jl) : __shfl(v1B, hc*8 + jl);
      bh8 vA = *(const bh8*)(H1 + (size_t)rowA*256 + cb);
      bh8 vB = *(const bh8*)(H1 + (size_t)rowB*256 + cb);
      #pragma unroll
      for (int c = 0; c < 8; c++){
        accA[c] += awA * b2f((unsigned short)vA[c]);
        accB[c] += awB * b2f((unsigned short)vB[c]);
      }
    }
    #pragma unroll
    for (int c = 0; c < 8; c++){
      accA[c] += __shfl_xor(accA[c], 32);
      accB[c] += __shfl_xor(accB[c], 32);
    }
    if (half == 0){
      bh8 oA, oB;
      #pragma unroll
      for (int c = 0; c < 8; c++){
        oA[c] = (short)f2b(elu1(accA[c]));
        oB[c] = (short)f2b(elu1(accB[c]));
      }
      *(bh8*)&Xt[lrA*264 + cb] = oA;
      *(bh8*)&Xt[lrB*264 + cb] = oB;
    }
  }
  __syncthreads();
  {
    int q = lane >> 4, l = lane & 15;
    bh8 a0[8], a1[8];
    #pragma unroll
    for (int kk = 0; kk < 8; kk++){
      a0[kk] = *(const bh8*)&Xt[l*264 + kk*32 + q*8];
      a1[kk] = *(const bh8*)&Xt[(16 + l)*264 + kk*32 + q*8];
    }
    const bh8* Wb = (const bh8*)Wt2;
    int ntt = (wv == 3) ? 2 : 1;
    for (int it = 0; it < ntt; it++){
      int tt = (it == 0) ? wv : 4;
      bh8 b[8];
      #pragma unroll
      for (int kk = 0; kk < 8; kk++) b[kk] = Wb[(size_t)(tt*16 + l)*32 + kk*4 + q];
      f4 c0 = {0.f,0.f,0.f,0.f}, c1 = {0.f,0.f,0.f,0.f};
      #pragma unroll
      for (int kk = 0; kk < 8; kk++){
        c0 = __builtin_amdgcn_mfma_f32_16x16x32_bf16(a0[kk], b[kk], c0, 0, 0, 0);
        c1 = __builtin_amdgcn_mfma_f32_16x16x32_bf16(a1[kk], b[kk], c1, 0, 0, 0);
      }
      if (tt < 4){
        #pragma unroll
        for (int r = 0; r < 4; r++){
          Hs[(q*4 + r)*88 + tt*16 + l]      = f2b(c0[r]);
          Hs[(16 + q*4 + r)*88 + tt*16 + l] = f2b(c1[r]);
        }
      } else if (l < 2){
        #pragma unroll
        for (int r = 0; r < 4; r++){
          int row0 = n0 + q*4 + r, row1 = n0 + 16 + q*4 + r;
          if (row0 < N) S2[(size_t)row0*2 + l] = c0[r];
          if (row1 < N) S2[(size_t)row1*2 + l] = c1[r];
        }
      }
    }
  }
  __syncthreads();
  {
    int r2 = tid >> 3, ch = tid & 7;
    int row = n0 + r2;
    if (row < N)
      *(bh8*)(H2 + (size_t)row*64 + ch*8) = *(const bh8*)&Hs[r2*88 + ch*8];
  }
}

// ---------------- agg2 v2 (unchanged): 2-node jam per wave, 16B gathers, ELU -> out ----
__global__ __launch_bounds__(256) void agg2_kernel(
    const float* __restrict__ S2, const unsigned short* __restrict__ H2,
    const int* __restrict__ dst, void* __restrict__ outv, int N,
    const void* __restrict__ W0){
  int tid = threadIdx.x, wv = tid >> 6, lane = tid & 63;
  int isf = detect_f32((const unsigned int*)W0, lane);
  int nodeA = blockIdx.x*8 + wv*2; if (nodeA > N-1) nodeA = N-1;
  int nodeB = nodeA + 1;           if (nodeB > N-1) nodeB = N-1;
  int j = lane & 15;
  int dA = dst[(size_t)nodeA*16 + j];
  int dB = dst[(size_t)nodeB*16 + j];
  float eA = lrelu(S2[(size_t)nodeA*2] + S2[(size_t)dA*2 + 1]);
  float eB = lrelu(S2[(size_t)nodeB*2] + S2[(size_t)dB*2 + 1]);
  float mA = eA, mB = eB;
  mA = fmaxf(mA, __shfl_xor(mA, 1)); mB = fmaxf(mB, __shfl_xor(mB, 1));
  mA = fmaxf(mA, __shfl_xor(mA, 2)); mB = fmaxf(mB, __shfl_xor(mB, 2));
  mA = fmaxf(mA, __shfl_xor(mA, 4)); mB = fmaxf(mB, __shfl_xor(mB, 4));
  mA = fmaxf(mA, __shfl_xor(mA, 8)); mB = fmaxf(mB, __shfl_xor(mB, 8));
  float pA = __expf(eA - mA), pB = __expf(eB - mB);
  float sA = pA, sB = pB;
  sA += __shfl_xor(sA, 1); sB += __shfl_xor(sB, 1);
  sA += __shfl_xor(sA, 2); sB += __shfl_xor(sB, 2);
  sA += __shfl_xor(sA, 4); sB += __shfl_xor(sB, 4);
  sA += __shfl_xor(sA, 8); sB += __shfl_xor(sB, 8);
  float attA = pA / sA, attB = pB / sB;
  int g = lane >> 3, cbl = (lane & 7)*8;
  float accA[8] = {0.f,0.f,0.f,0.f,0.f,0.f,0.f,0.f};
  float accB[8] = {0.f,0.f,0.f,0.f,0.f,0.f,0.f,0.f};
  #pragma unroll
  for (int it = 0; it < 2; it++){
    int j2 = it*8 + g;
    float awA = __shfl(attA, j2), awB = __shfl(attB, j2);
    int rowA  = __shfl(dA,   j2), rowB  = __shfl(dB,   j2);
    bh8 vA = *(const bh8*)(H2 + (size_t)rowA*64 + cbl);
    bh8 vB = *(const bh8*)(H2 + (size_t)rowB*64 + cbl);
    #pragma unroll
    for (int c = 0; c < 8; c++){
      accA[c] += awA * b2f((unsigned short)vA[c]);
      accB[c] += awB * b2f((unsigned short)vB[c]);
    }
  }
  #pragma unroll
  for (int c = 0; c < 8; c++){
    accA[c] += __shfl_xor(accA[c], 8);  accB[c] += __shfl_xor(accB[c], 8);
    accA[c] += __shfl_xor(accA[c], 16); accB[c] += __shfl_xor(accB[c], 16);
    accA[c] += __shfl_xor(accA[c], 32); accB[c] += __shfl_xor(accB[c], 32);
  }
  if (lane < 8){
    size_t oiA = (size_t)nodeA*64 + cbl;
    size_t oiB = (size_t)nodeB*64 + cbl;
    if (isf){
      float4 a0v, a1v, b0v, b1v;
      a0v.x = elu1(accA[0]); a0v.y = elu1(accA[1]); a0v.z = elu1(accA[2]); a0v.w = elu1(accA[3]);
      a1v.x = elu1(accA[4]); a1v.y = elu1(accA[5]); a1v.z = elu1(accA[6]); a1v.w = elu1(accA[7]);
      b0v.x = elu1(accB[0]); b0v.y = elu1(accB[1]); b0v.z = elu1(accB[2]); b0v.w = elu1(accB[3]);
      b1v.x = elu1(accB[4]); b1v.y = elu1(accB[5]); b1v.z = elu1(accB[6]); b1v.w = elu1(accB[7]);
      *(float4*)((float*)outv + oiA)     = a0v;
      *(float4*)((float*)outv + oiA + 4) = a1v;
      *(float4*)((float*)outv + oiB)     = b0v;
      *(float4*)((float*)outv + oiB + 4) = b1v;
    } else {
      bh8 oA, oB;
      #pragma unroll
      for (int c = 0; c < 8; c++){
        oA[c] = (short)f2b(elu1(accA[c]));
        oB[c] = (short)f2b(elu1(accB[c]));
      }
      *(bh8*)((unsigned short*)outv + oiA) = oA;
      *(bh8*)((unsigned short*)outv + oiB) = oB;
    }
  }
}

extern "C" void kernel_launch(void* const* d_in, const int* in_sizes, int n_in,
                              void* d_out, int out_size, void* d_ws, size_t ws_size,
                              hipStream_t stream){
  const void* X  = d_in[0];
  const int*  ed = (const int*)d_in[1];
  const void* W0 = d_in[2];
  const void* a0 = d_in[3];
  const void* W1 = d_in[4];
  const void* a1 = d_in[5];

  int N = in_sizes[0] / 256;       // 50000
  int E = N * 16;
  const int* dst = ed + E;         // edges[1]; src is structurally e>>4

  char* w = (char*)d_ws;
  size_t off = 0;
  auto alloc = [&](size_t bytes) -> void* {
    void* p = w + off; off += (bytes + 255) & ~(size_t)255; return p;
  };
  unsigned short* Wt1 = (unsigned short*)alloc(272*256*2);
  unsigned short* Wt2 = (unsigned short*)alloc(80*256*2);
  float*          S1  = (float*)alloc((size_t)N*16*4);
  unsigned short* H1  = (unsigned short*)alloc((size_t)N*256*2);
  unsigned short* H2  = (unsigned short*)alloc((size_t)N*64*2);
  float*          S2  = (float*)alloc((size_t)N*2*4);
  (void)ws_size; (void)n_in; (void)out_size;

  int g1 = (N + 111) / 112;
  int gf = (N + 31) / 32;          // 1563 total fused blocks
  int gfa = gf / 2;                // first half
  int gfb = gf - gfa;              // second half
  int ab = (N + 7) / 8;
  prep_kernel     <<<352,256, 0, stream>>>(W0, a0, W1, a1, Wt1, Wt2);
  gemm1_mfma      <<<g1, 256, 0, stream>>>(X,  Wt1, H1, S1, N, W0);
  fused_agg1_gemm2<<<gfa,256, 0, stream>>>(S1, H1, dst, Wt2, H2, S2, N, 0);
  fused_agg1_gemm2<<<gfb,256, 0, stream>>>(S1, H1, dst, Wt2, H2, S2, N, gfa);
  agg2_kernel     <<<ab, 256, 0, stream>>>(S2, H2, dst, d_out, N, W0);
}

// Round 12
// 221.599 us; speedup vs baseline: 1.0219x; 1.0219x over previous
//
#include <hip/hip_runtime.h>

typedef __attribute__((ext_vector_type(8))) short bh8;   // 8 x bf16 (16B)
typedef __attribute__((ext_vector_type(4))) float f4;

static __device__ __forceinline__ float b2f(unsigned short u){
  union { unsigned int i; float f; } c; c.i = ((unsigned int)u) << 16; return c.f;
}
static __device__ __forceinline__ unsigned short f2b(float f){
  union { float f; unsigned int i; } c; c.f = f;
  unsigned int u = c.i; u += 0x7fffu + ((u >> 16) & 1u);
  return (unsigned short)(u >> 16);
}
static __device__ __forceinline__ float elu1(float x){ return x > 0.f ? x : (__expf(x) - 1.f); }
static __device__ __forceinline__ float lrelu(float x){ return x > 0.f ? x : 0.2f * x; }
static __device__ __forceinline__ float gload(const void* p, size_t i, int isf32){
  return isf32 ? ((const float*)p)[i] : b2f(((const unsigned short*)p)[i]);
}
// per-wave dtype vote: sample 64 words of W0; bf16 -> low u16 is a plausible small
// bf16 (exp 100..126) ~64/64; fp32 -> low u16 is mantissa noise (~10%).
static __device__ __forceinline__ int detect_f32(const unsigned int* __restrict__ W0w, int lane){
  unsigned int w = W0w[lane & 63];
  unsigned int e = (w >> 7) & 0xFFu;
  unsigned long long m = __ballot(e >= 100u && e <= 126u);
  return (__popcll(m) < 32) ? 1 : 0;
}

// ---------------- prep: bf16 transposed + augmented weight tables ----------------
// Wt1 [272][256]: c<256 -> W0[h=c>>5][k][d=c&31]
//                 c in [256,264): h: sum_d W0[h][k][d]*a0[h][d]      (s_src)
//                 c in [264,272): h: sum_d W0[h][k][d]*a0[h][32+d]   (s_dst)
// Wt2 [80][256]:  c<64 -> W1[k][c]; c==64: W1[k][:].a1[:64]; c==65: .a1[64:]; rest 0
__global__ __launch_bounds__(256) void prep_kernel(
    const void* __restrict__ W0, const void* __restrict__ a0,
    const void* __restrict__ W1, const void* __restrict__ a1,
    unsigned short* __restrict__ Wt1, unsigned short* __restrict__ Wt2){
  int isf = detect_f32((const unsigned int*)W0, threadIdx.x & 63);
  int c = blockIdx.x, k = threadIdx.x;
  if (c < 272){
    float v;
    if (c < 256){
      int h = c >> 5, d = c & 31;
      v = gload(W0, (size_t)(h*256 + k)*32 + d, isf);
    } else if (c < 264){
      int h = c - 256; float s = 0.f;
      for (int d = 0; d < 32; d++)
        s += gload(W0, (size_t)(h*256 + k)*32 + d, isf) * gload(a0, h*64 + d, isf);
      v = s;
    } else {
      int h = c - 264; float s = 0.f;
      for (int d = 0; d < 32; d++)
        s += gload(W0, (size_t)(h*256 + k)*32 + d, isf) * gload(a0, h*64 + 32 + d, isf);
      v = s;
    }
    Wt1[c*256 + k] = f2b(v);
  } else {
    int c2 = c - 272; float v;
    if (c2 < 64) v = gload(W1, k*64 + c2, isf);
    else if (c2 == 64){ float s = 0.f; for (int i = 0; i < 64; i++) s += gload(W1, k*64+i, isf) * gload(a1, i, isf);      v = s; }
    else if (c2 == 65){ float s = 0.f; for (int i = 0; i < 64; i++) s += gload(W1, k*64+i, isf) * gload(a1, 64 + i, isf); v = s; }
    else v = 0.f;
    Wt2[c2*256 + k] = f2b(v);
  }
}

// ---------------- GEMM1 v5: 64-row LDS A-tile (better grid/occupancy), register B ----
// Grid 782 (~3 blocks/CU vs v4's 1.75), LDS 33.8KB (4 blocks/CU static), 4 m-iters.
__global__ __launch_bounds__(256) void gemm1_mfma(
    const void* __restrict__ Xraw, const unsigned short* __restrict__ Wt,
    unsigned short* __restrict__ H1, float* __restrict__ S1, int N,
    const void* __restrict__ W0){
  __shared__ __align__(16) unsigned short A[64*264];
  int tid = threadIdx.x, wv = tid >> 6, lane = tid & 63;
  int isf = detect_f32((const unsigned int*)W0, lane);
  int q = lane >> 4, l = lane & 15;
  int n0 = blockIdx.x*64;
  // ---- stage A (64 x 256 bf16, LDS stride 264) ----
  #pragma unroll
  for (int it = 0; it < 8; it++){
    int g = it*256 + tid;
    int r = g >> 5, c = g & 31;
    int grow = n0 + r; if (grow > N-1) grow = N-1;
    bh8 v;
    if (isf){
      const float* xr = (const float*)Xraw + (size_t)grow*256 + c*8;
      float4 u0 = *(const float4*)xr, u1 = *(const float4*)(xr + 4);
      v[0]=(short)f2b(u0.x); v[1]=(short)f2b(u0.y); v[2]=(short)f2b(u0.z); v[3]=(short)f2b(u0.w);
      v[4]=(short)f2b(u1.x); v[5]=(short)f2b(u1.y); v[6]=(short)f2b(u1.z); v[7]=(short)f2b(u1.w);
    } else {
      v = *(const bh8*)((const unsigned short*)Xraw + (size_t)grow*256 + c*8);
    }
    *(bh8*)&A[r*264 + c*8] = v;
  }
  __syncthreads();
  // ---- B tiles register-resident (4 per wave); wave 0 also the score tile ----
  const bh8* Wb = (const bh8*)Wt;
  bh8 B[4][8];
  #pragma unroll
  for (int tt = 0; tt < 4; tt++){
    int t = wv*4 + tt;
    #pragma unroll
    for (int kk = 0; kk < 8; kk++) B[tt][kk] = Wb[(size_t)(t*16 + l)*32 + kk*4 + q];
  }
  bh8 Bs[8];
  if (wv == 0){
    #pragma unroll
    for (int kk = 0; kk < 8; kk++) Bs[kk] = Wb[(size_t)(256 + l)*32 + kk*4 + q];
  }
  // ---- main loop over 4 m-tiles, C written in-place into A ----
  for (int m = 0; m < 4; m++){
    bh8 a[8];
    #pragma unroll
    for (int kk = 0; kk < 8; kk++) a[kk] = *(const bh8*)&A[(m*16 + l)*264 + kk*32 + q*8];
    f4 acc[4];
    #pragma unroll
    for (int tt = 0; tt < 4; tt++){
      f4 z = {0.f,0.f,0.f,0.f}; acc[tt] = z;
      #pragma unroll
      for (int kk = 0; kk < 8; kk++)
        acc[tt] = __builtin_amdgcn_mfma_f32_16x16x32_bf16(a[kk], B[tt][kk], acc[tt], 0, 0, 0);
    }
    if (wv == 0){
      f4 as = {0.f,0.f,0.f,0.f};
      #pragma unroll
      for (int kk = 0; kk < 8; kk++)
        as = __builtin_amdgcn_mfma_f32_16x16x32_bf16(a[kk], Bs[kk], as, 0, 0, 0);
      #pragma unroll
      for (int r = 0; r < 4; r++){
        int row = n0 + m*16 + q*4 + r;
        if (row < N) S1[(size_t)row*16 + l] = as[r];   // l<8: s_src[h], l>=8: s_dst[h]
      }
    }
    __syncthreads();                       // all reads of A[m] complete
    #pragma unroll
    for (int tt = 0; tt < 4; tt++){
      int t = wv*4 + tt;
      #pragma unroll
      for (int r = 0; r < 4; r++)
        A[(m*16 + q*4 + r)*264 + t*16 + l] = f2b(acc[tt][r]);
    }
    __syncthreads();                       // all writes to A[m] complete
  }
  // ---- bulk coalesced H1 store ----
  #pragma unroll
  for (int g = 0; g < 8; g++){
    int idx = g*256 + tid;
    int r = idx >> 5, c = idx & 31;
    int row = n0 + r;
    if (row < N)
      *(bh8*)(H1 + (size_t)row*256 + c*8) = *(const bh8*)&A[r*264 + c*8];
  }
}

// ---------------- FUSED agg1 + gemm2 (R9 single-dispatch 32-node version) ----------------
__global__ __launch_bounds__(256) void fused_agg1_gemm2(
    const float* __restrict__ S1, const unsigned short* __restrict__ H1,
    const int* __restrict__ dst, const unsigned short* __restrict__ Wt2,
    unsigned short* __restrict__ H2, float* __restrict__ S2, int N){
  __shared__ __align__(16) unsigned short Xt[32*264];
  __shared__ __align__(16) unsigned short Hs[32*88];
  int tid = threadIdx.x, wv = tid >> 6, lane = tid & 63;
  int n0 = blockIdx.x*32;
  int h = lane >> 3, jj = lane & 7;
  int half = lane >> 5, li = lane & 31;
  int cb = li*8, hc = li >> 2;
  for (int np = 0; np < 4; np++){
    int lrA = wv*8 + np*2, lrB = lrA + 1;
    int nodeA = n0 + lrA; if (nodeA > N-1) nodeA = N-1;
    int nodeB = n0 + lrB; if (nodeB > N-1) nodeB = N-1;
    const int* dpA = dst + (size_t)nodeA*16;
    const int* dpB = dst + (size_t)nodeB*16;
    int d0A = dpA[jj], d1A = dpA[jj + 8];
    int d0B = dpB[jj], d1B = dpB[jj + 8];
    float ssA = S1[(size_t)nodeA*16 + h];
    float ssB = S1[(size_t)nodeB*16 + h];
    float e0A = lrelu(ssA + S1[(size_t)d0A*16 + 8 + h]);
    float e1A = lrelu(ssA + S1[(size_t)d1A*16 + 8 + h]);
    float e0B = lrelu(ssB + S1[(size_t)d0B*16 + 8 + h]);
    float e1B = lrelu(ssB + S1[(size_t)d1B*16 + 8 + h]);
    float mA = fmaxf(e0A, e1A), mB = fmaxf(e0B, e1B);
    mA = fmaxf(mA, __shfl_xor(mA, 1)); mB = fmaxf(mB, __shfl_xor(mB, 1));
    mA = fmaxf(mA, __shfl_xor(mA, 2)); mB = fmaxf(mB, __shfl_xor(mB, 2));
    mA = fmaxf(mA, __shfl_xor(mA, 4)); mB = fmaxf(mB, __shfl_xor(mB, 4));
    float p0A = __expf(e0A - mA), p1A = __expf(e1A - mA);
    float p0B = __expf(e0B - mB), p1B = __expf(e1B - mB);
    float sA = p0A + p1A, sB = p0B + p1B;
    sA += __shfl_xor(sA, 1); sB += __shfl_xor(sB, 1);
    sA += __shfl_xor(sA, 2); sB += __shfl_xor(sB, 2);
    sA += __shfl_xor(sA, 4); sB += __shfl_xor(sB, 4);
    float invA = 1.f / sA, invB = 1.f / sB;
    float v0A = p0A * invA, v1A = p1A * invA;
    float v0B = p0B * invB, v1B = p1B * invB;
    float accA[8] = {0.f,0.f,0.f,0.f,0.f,0.f,0.f,0.f};
    float accB[8] = {0.f,0.f,0.f,0.f,0.f,0.f,0.f,0.f};
    #pragma unroll
    for (int i = 0; i < 8; i++){
      int j  = i*2 + half;
      int jl = j & 7;
      int rowA  = (i < 4) ? __shfl(d0A, jl) : __shfl(d1A, jl);
      int rowB  = (i < 4) ? __shfl(d0B, jl) : __shfl(d1B, jl);
      float awA = (i < 4) ? __shfl(v0A, hc*8 + jl) : __shfl(v1A, hc*8 + jl);
      float awB = (i < 4) ? __shfl(v0B, hc*8 + jl) : __shfl(v1B, hc*8 + jl);
      bh8 vA = *(const bh8*)(H1 + (size_t)rowA*256 + cb);
      bh8 vB = *(const bh8*)(H1 + (size_t)rowB*256 + cb);
      #pragma unroll
      for (int c = 0; c < 8; c++){
        accA[c] += awA * b2f((unsigned short)vA[c]);
        accB[c] += awB * b2f((unsigned short)vB[c]);
      }
    }
    #pragma unroll
    for (int c = 0; c < 8; c++){
      accA[c] += __shfl_xor(accA[c], 32);
      accB[c] += __shfl_xor(accB[c], 32);
    }
    if (half == 0){
      bh8 oA, oB;
      #pragma unroll
      for (int c = 0; c < 8; c++){
        oA[c] = (short)f2b(elu1(accA[c]));
        oB[c] = (short)f2b(elu1(accB[c]));
      }
      *(bh8*)&Xt[lrA*264 + cb] = oA;
      *(bh8*)&Xt[lrB*264 + cb] = oB;
    }
  }
  __syncthreads();
  {
    int q = lane >> 4, l = lane & 15;
    bh8 a0[8], a1[8];
    #pragma unroll
    for (int kk = 0; kk < 8; kk++){
      a0[kk] = *(const bh8*)&Xt[l*264 + kk*32 + q*8];
      a1[kk] = *(const bh8*)&Xt[(16 + l)*264 + kk*32 + q*8];
    }
    const bh8* Wb = (const bh8*)Wt2;
    int ntt = (wv == 3) ? 2 : 1;
    for (int it = 0; it < ntt; it++){
      int tt = (it == 0) ? wv : 4;
      bh8 b[8];
      #pragma unroll
      for (int kk = 0; kk < 8; kk++) b[kk] = Wb[(size_t)(tt*16 + l)*32 + kk*4 + q];
      f4 c0 = {0.f,0.f,0.f,0.f}, c1 = {0.f,0.f,0.f,0.f};
      #pragma unroll
      for (int kk = 0; kk < 8; kk++){
        c0 = __builtin_amdgcn_mfma_f32_16x16x32_bf16(a0[kk], b[kk], c0, 0, 0, 0);
        c1 = __builtin_amdgcn_mfma_f32_16x16x32_bf16(a1[kk], b[kk], c1, 0, 0, 0);
      }
      if (tt < 4){
        #pragma unroll
        for (int r = 0; r < 4; r++){
          Hs[(q*4 + r)*88 + tt*16 + l]      = f2b(c0[r]);
          Hs[(16 + q*4 + r)*88 + tt*16 + l] = f2b(c1[r]);
        }
      } else if (l < 2){
        #pragma unroll
        for (int r = 0; r < 4; r++){
          int row0 = n0 + q*4 + r, row1 = n0 + 16 + q*4 + r;
          if (row0 < N) S2[(size_t)row0*2 + l] = c0[r];
          if (row1 < N) S2[(size_t)row1*2 + l] = c1[r];
        }
      }
    }
  }
  __syncthreads();
  {
    int r2 = tid >> 3, ch = tid & 7;
    int row = n0 + r2;
    if (row < N)
      *(bh8*)(H2 + (size_t)row*64 + ch*8) = *(const bh8*)&Hs[r2*88 + ch*8];
  }
}

// ---------------- agg2 v2 (unchanged): 2-node jam per wave, 16B gathers, ELU -> out ----
__global__ __launch_bounds__(256) void agg2_kernel(
    const float* __restrict__ S2, const unsigned short* __restrict__ H2,
    const int* __restrict__ dst, void* __restrict__ outv, int N,
    const void* __restrict__ W0){
  int tid = threadIdx.x, wv = tid >> 6, lane = tid & 63;
  int isf = detect_f32((const unsigned int*)W0, lane);
  int nodeA = blockIdx.x*8 + wv*2; if (nodeA > N-1) nodeA = N-1;
  int nodeB = nodeA + 1;           if (nodeB > N-1) nodeB = N-1;
  int j = lane & 15;
  int dA = dst[(size_t)nodeA*16 + j];
  int dB = dst[(size_t)nodeB*16 + j];
  float eA = lrelu(S2[(size_t)nodeA*2] + S2[(size_t)dA*2 + 1]);
  float eB = lrelu(S2[(size_t)nodeB*2] + S2[(size_t)dB*2 + 1]);
  float mA = eA, mB = eB;
  mA = fmaxf(mA, __shfl_xor(mA, 1)); mB = fmaxf(mB, __shfl_xor(mB, 1));
  mA = fmaxf(mA, __shfl_xor(mA, 2)); mB = fmaxf(mB, __shfl_xor(mB, 2));
  mA = fmaxf(mA, __shfl_xor(mA, 4)); mB = fmaxf(mB, __shfl_xor(mB, 4));
  mA = fmaxf(mA, __shfl_xor(mA, 8)); mB = fmaxf(mB, __shfl_xor(mB, 8));
  float pA = __expf(eA - mA), pB = __expf(eB - mB);
  float sA = pA, sB = pB;
  sA += __shfl_xor(sA, 1); sB += __shfl_xor(sB, 1);
  sA += __shfl_xor(sA, 2); sB += __shfl_xor(sB, 2);
  sA += __shfl_xor(sA, 4); sB += __shfl_xor(sB, 4);
  sA += __shfl_xor(sA, 8); sB += __shfl_xor(sB, 8);
  float attA = pA / sA, attB = pB / sB;
  int g = lane >> 3, cbl = (lane & 7)*8;
  float accA[8] = {0.f,0.f,0.f,0.f,0.f,0.f,0.f,0.f};
  float accB[8] = {0.f,0.f,0.f,0.f,0.f,0.f,0.f,0.f};
  #pragma unroll
  for (int it = 0; it < 2; it++){
    int j2 = it*8 + g;
    float awA = __shfl(attA, j2), awB = __shfl(attB, j2);
    int rowA  = __shfl(dA,   j2), rowB  = __shfl(dB,   j2);
    bh8 vA = *(const bh8*)(H2 + (size_t)rowA*64 + cbl);
    bh8 vB = *(const bh8*)(H2 + (size_t)rowB*64 + cbl);
    #pragma unroll
    for (int c = 0; c < 8; c++){
      accA[c] += awA * b2f((unsigned short)vA[c]);
      accB[c] += awB * b2f((unsigned short)vB[c]);
    }
  }
  #pragma unroll
  for (int c = 0; c < 8; c++){
    accA[c] += __shfl_xor(accA[c], 8);  accB[c] += __shfl_xor(accB[c], 8);
    accA[c] += __shfl_xor(accA[c], 16); accB[c] += __shfl_xor(accB[c], 16);
    accA[c] += __shfl_xor(accA[c], 32); accB[c] += __shfl_xor(accB[c], 32);
  }
  if (lane < 8){
    size_t oiA = (size_t)nodeA*64 + cbl;
    size_t oiB = (size_t)nodeB*64 + cbl;
    if (isf){
      float4 a0v, a1v, b0v, b1v;
      a0v.x = elu1(accA[0]); a0v.y = elu1(accA[1]); a0v.z = elu1(accA[2]); a0v.w = elu1(accA[3]);
      a1v.x = elu1(accA[4]); a1v.y = elu1(accA[5]); a1v.z = elu1(accA[6]); a1v.w = elu1(accA[7]);
      b0v.x = elu1(accB[0]); b0v.y = elu1(accB[1]); b0v.z = elu1(accB[2]); b0v.w = elu1(accB[3]);
      b1v.x = elu1(accB[4]); b1v.y = elu1(accB[5]); b1v.z = elu1(accB[6]); b1v.w = elu1(accB[7]);
      *(float4*)((float*)outv + oiA)     = a0v;
      *(float4*)((float*)outv + oiA + 4) = a1v;
      *(float4*)((float*)outv + oiB)     = b0v;
      *(float4*)((float*)outv + oiB + 4) = b1v;
    } else {
      bh8 oA, oB;
      #pragma unroll
      for (int c = 0; c < 8; c++){
        oA[c] = (short)f2b(elu1(accA[c]));
        oB[c] = (short)f2b(elu1(accB[c]));
      }
      *(bh8*)((unsigned short*)outv + oiA) = oA;
      *(bh8*)((unsigned short*)outv + oiB) = oB;
    }
  }
}

extern "C" void kernel_launch(void* const* d_in, const int* in_sizes, int n_in,
                              void* d_out, int out_size, void* d_ws, size_t ws_size,
                              hipStream_t stream){
  const void* X  = d_in[0];
  const int*  ed = (const int*)d_in[1];
  const void* W0 = d_in[2];
  const void* a0 = d_in[3];
  const void* W1 = d_in[4];
  const void* a1 = d_in[5];

  int N = in_sizes[0] / 256;       // 50000
  int E = N * 16;
  const int* dst = ed + E;         // edges[1]; src is structurally e>>4

  char* w = (char*)d_ws;
  size_t off = 0;
  auto alloc = [&](size_t bytes) -> void* {
    void* p = w + off; off += (bytes + 255) & ~(size_t)255; return p;
  };
  unsigned short* Wt1 = (unsigned short*)alloc(272*256*2);
  unsigned short* Wt2 = (unsigned short*)alloc(80*256*2);
  float*          S1  = (float*)alloc((size_t)N*16*4);
  unsigned short* H1  = (unsigned short*)alloc((size_t)N*256*2);
  unsigned short* H2  = (unsigned short*)alloc((size_t)N*64*2);
  float*          S2  = (float*)alloc((size_t)N*2*4);
  (void)ws_size; (void)n_in; (void)out_size;

  int g1 = (N + 63) / 64;          // 782 blocks (~3/CU)
  int gf = (N + 31) / 32;
  int ab = (N + 7) / 8;
  prep_kernel     <<<352,256, 0, stream>>>(W0, a0, W1, a1, Wt1, Wt2);
  gemm1_mfma      <<<g1, 256, 0, stream>>>(X,  Wt1, H1, S1, N, W0);
  fused_agg1_gemm2<<<gf, 256, 0, stream>>>(S1, H1, dst, Wt2, H2, S2, N);
  agg2_kernel     <<<ab, 256, 0, stream>>>(S2, H2, dst, d_out, N, W0);
}